// Round 3
// baseline (1480.910 us; speedup 1.0000x reference)
//
#include <hip/hip_runtime.h>

#define DEVFN __device__ __forceinline__

constexpr int C   = 64;
constexpr int Hh  = 160, Ww = 160, HW = Hh * Ww;   // 25600
constexpr int B   = 2;
constexpr int P   = B * HW;                        // 51200
constexpr int NSET = 32;

// K1: LayerNorm over channels per pixel
__global__ void k1_ln1(const float* __restrict__ inp, const float* __restrict__ lnw,
                       const float* __restrict__ lnb, float* __restrict__ x1) {
    int p = blockIdx.x * 256 + threadIdx.x;
    int b = p / HW, hw = p % HW;
    const float* src = inp + (size_t)b * C * HW + hw;
    float v[64];
    float s = 0.f, s2 = 0.f;
#pragma unroll
    for (int c = 0; c < 64; c++) {
        float f = src[c * HW];
        v[c] = f; s += f; s2 += f * f;
    }
    float mu  = s * (1.f / 64.f);
    float var = fmaxf(s2 * (1.f / 64.f) - mu * mu, 0.f);
    float r   = rsqrtf(var + 1e-6f);
    float* dst = x1 + (size_t)b * C * HW + hw;
#pragma unroll
    for (int c = 0; c < 64; c++)
        dst[c * HW] = (v[c] - mu) * r * lnw[c] + lnb[c];
}

// K2: spatial mean of x1 per (b,c)
__global__ void k2_mean(const float* __restrict__ x1, float* __restrict__ meanb) {
    int bc = blockIdx.x;                         // 0..127
    const float* src = x1 + (size_t)bc * HW;
    float s = 0.f;
    for (int i = threadIdx.x; i < HW; i += 256) s += src[i];
#pragma unroll
    for (int o = 32; o > 0; o >>= 1) s += __shfl_down(s, o);
    __shared__ float red[4];
    if ((threadIdx.x & 63) == 0) red[threadIdx.x >> 6] = s;
    __syncthreads();
    if (threadIdx.x == 0)
        meanb[bc] = (red[0] + red[1] + red[2] + red[3]) * (1.f / HW);
}

// K3: sca = sca_w @ mean + sca_b   [B,64]
__global__ void k3_sca(const float* __restrict__ scaw, const float* __restrict__ scab_,
                       const float* __restrict__ meanb, float* __restrict__ sca) {
    int t = threadIdx.x;
    if (t >= 128) return;
    int b = t >> 6, c = t & 63;
    float acc = scab_[c];
#pragma unroll
    for (int k = 0; k < 64; k++)
        acc = fmaf(scaw[c * 64 + k], meanb[b * 64 + k], acc);
    sca[t] = acc;
}

// helper for K4: 3x3 grouped conv taps (groups=32, 2 in-ch per out-ch)
template <bool INT_>
DEVFN void att_taps(const float* __restrict__ xb, int h, int w,
                    const float* __restrict__ c2aw, const float* __restrict__ c2ab,
                    float* t) {
#pragma unroll
    for (int o = 0; o < 32; o++) {
        float acc = c2ab[o];
#pragma unroll
        for (int k = 0; k < 2; k++) {
            const float* xc = xb + (size_t)(2 * o + k) * HW;
            const float* wr = c2aw + (o * 2 + k) * 9;
#pragma unroll
            for (int kh = 0; kh < 3; kh++) {
                int y = h + kh - 1;
#pragma unroll
                for (int kw = 0; kw < 3; kw++) {
                    int x = w + kw - 1;
                    if (INT_ || ((unsigned)y < (unsigned)Hh && (unsigned)x < (unsigned)Ww))
                        acc = fmaf(wr[kh * 3 + kw], xc[y * Ww + x], acc);
                }
            }
        }
        t[o] = acc;
    }
}

// K4: att = (1x1 conv(simple_gate(grouped 3x3 conv(x1)))) * attgamma
__global__ void k4_att(const float* __restrict__ x1, const float* __restrict__ c2aw,
                       const float* __restrict__ c2ab, const float* __restrict__ c2bw,
                       const float* __restrict__ c2bb, const float* __restrict__ attg,
                       float* __restrict__ att) {
    int p = blockIdx.x * 256 + threadIdx.x;
    int b = p / HW, hw = p % HW, h = hw / Ww, w = hw % Ww;
    const float* xb = x1 + (size_t)b * C * HW;
    float t[32];
    bool interior = (h >= 1 && h < Hh - 1 && w >= 1 && w < Ww - 1);
    if (interior) att_taps<true>(xb, h, w, c2aw, c2ab, t);
    else          att_taps<false>(xb, h, w, c2aw, c2ab, t);
    float g[16];
#pragma unroll
    for (int c = 0; c < 16; c++) g[c] = t[c] * t[c + 16];
#pragma unroll 1
    for (int s = 0; s < 32; s++) {
        float acc = c2bb[s];
#pragma unroll
        for (int c = 0; c < 16; c++)
            acc = fmaf(c2bw[s * 16 + c], g[c], acc);
        att[(size_t)(b * NSET + s) * HW + hw] = acc * attg[s];
    }
}

// K5: u1 = 1x1 conv (64x64) of x1
__global__ void k5_u1(const float* __restrict__ x1, const float* __restrict__ w,
                      const float* __restrict__ bias, float* __restrict__ u1) {
    int p = blockIdx.x * 256 + threadIdx.x;
    int b = p / HW, hw = p % HW;
    const float* xc = x1 + (size_t)b * C * HW + hw;
    float xin[64];
#pragma unroll
    for (int c = 0; c < 64; c++) xin[c] = xc[c * HW];
    float* dst = u1 + (size_t)b * C * HW + hw;
#pragma unroll 1
    for (int co = 0; co < 64; co++) {
        float acc = bias[co];
        const float* wr = w + co * 64;
#pragma unroll
        for (int ci = 0; ci < 64; ci++) acc = fmaf(wr[ci], xin[ci], acc);
        dst[co * HW] = acc;
    }
}

// K6: uf = 5x5 grouped conv (groups=16, 4in/4out) of u1, pad=2
__global__ void k6_uf(const float* __restrict__ u1, const float* __restrict__ w,
                      const float* __restrict__ bias, float* __restrict__ uf) {
    int lane = threadIdx.x & 63, wq = threadIdx.x >> 6;
    int p = blockIdx.x * 64 + lane;
    int b = p / HW, hw = p % HW, h = hw / Ww, w_ = hw % Ww;
    bool interior = (h >= 2 && h < Hh - 2 && w_ >= 2 && w_ < Ww - 2);
#pragma unroll 1
    for (int gi = 0; gi < 4; gi++) {
        int g = wq * 4 + gi;
        float acc[4];
#pragma unroll
        for (int o = 0; o < 4; o++) acc[o] = bias[g * 4 + o];
#pragma unroll 1
        for (int cl = 0; cl < 4; cl++) {
            int ci = g * 4 + cl;
            const float* src = u1 + (size_t)(b * C + ci) * HW;
            float tv[25];
            if (interior) {
#pragma unroll
                for (int kh = 0; kh < 5; kh++)
#pragma unroll
                    for (int kw = 0; kw < 5; kw++)
                        tv[kh * 5 + kw] = src[(h + kh - 2) * Ww + (w_ + kw - 2)];
            } else {
#pragma unroll
                for (int kh = 0; kh < 5; kh++) {
                    int y = h + kh - 2;
#pragma unroll
                    for (int kw = 0; kw < 5; kw++) {
                        int x = w_ + kw - 2;
                        tv[kh * 5 + kw] =
                            ((unsigned)y < (unsigned)Hh && (unsigned)x < (unsigned)Ww)
                                ? src[y * Ww + x] : 0.f;
                    }
                }
            }
#pragma unroll
            for (int o = 0; o < 4; o++) {
                const float* wr = w + ((g * 4 + o) * 4 + cl) * 25;
#pragma unroll
                for (int tp = 0; tp < 25; tp++) acc[o] = fmaf(wr[tp], tv[tp], acc[o]);
            }
        }
        float* dst = uf + (size_t)(b * C + g * 4) * HW + hw;
#pragma unroll
        for (int o = 0; o < 4; o++) dst[o * HW] = acc[o];
    }
}

// K7: KBA + ga1 + residual uf + sca scaling   -> xmid
__global__ void k7_kba(const float* __restrict__ att, const float* __restrict__ uf,
                       const float* __restrict__ kbw, const float* __restrict__ kbb,
                       const float* __restrict__ ga1, const float* __restrict__ sca,
                       float* __restrict__ xmid) {
    int lane = threadIdx.x & 63, wv = threadIdx.x >> 6;
    int blk = blockIdx.x;                          // 0..1599
    int pblk = (blk >= 800) ? blk - 800 : blk;
    int wq = ((blk >= 800) ? 4 : 0) + wv;          // 0..7
    int p = pblk * 64 + lane;
    int b = p / HW, hw = p % HW, h = hw / Ww, w = hw % Ww;

    float a[32];
    const float* asrc = att + (size_t)b * NSET * HW + hw;
#pragma unroll
    for (int s = 0; s < 32; s++) a[s] = asrc[s * HW];

    bool interior = (h >= 1 && h < Hh - 1 && w >= 1 && w < Ww - 1);

#pragma unroll 1
    for (int gi = 0; gi < 2; gi++) {
        int g = wq * 2 + gi;
        float u[36];
#pragma unroll
        for (int cl = 0; cl < 4; cl++) {
            const float* src = uf + (size_t)(b * C + g * 4 + cl) * HW;
            if (interior) {
#pragma unroll
                for (int kh = 0; kh < 3; kh++)
#pragma unroll
                    for (int kw = 0; kw < 3; kw++)
                        u[cl * 9 + kh * 3 + kw] = src[(h + kh - 1) * Ww + (w + kw - 1)];
            } else {
#pragma unroll
                for (int kh = 0; kh < 3; kh++) {
                    int y = h + kh - 1;
#pragma unroll
                    for (int kw = 0; kw < 3; kw++) {
                        int x = w + kw - 1;
                        u[cl * 9 + kh * 3 + kw] =
                            ((unsigned)y < (unsigned)Hh && (unsigned)x < (unsigned)Ww)
                                ? src[y * Ww + x] : 0.f;
                    }
                }
            }
        }
#pragma unroll 1
        for (int o = 0; o < 4; o++) {
            int co = g * 4 + o;
            const float* wr = kbw + g * 144 + o * 36;
            float acc = 0.f;
#pragma unroll 1
            for (int s = 0; s < 32; s++) {
                const float* ws_ = wr + s * 2304;
                float dot = ws_[0] * u[0];
#pragma unroll
                for (int i = 1; i < 36; i++) dot = fmaf(ws_[i], u[i], dot);
                acc = fmaf(a[s], dot, acc);
            }
            float bsum = 0.f;
#pragma unroll
            for (int s = 0; s < 32; s++)
                bsum = fmaf(a[s], kbb[s * 64 + co], bsum);
            float outv = (acc + bsum) * ga1[co] + u[o * 9 + 4];
            outv *= sca[b * 64 + co];
            xmid[(size_t)(b * C + co) * HW + hw] = outv;
        }
    }
}

// K8: conv3 (1x1 64x64) + residual:  y = inp + conv3(xmid)*beta
__global__ void k8_conv3(const float* __restrict__ xmid, const float* __restrict__ inp,
                         const float* __restrict__ w, const float* __restrict__ bias,
                         const float* __restrict__ beta, float* __restrict__ y) {
    int p = blockIdx.x * 256 + threadIdx.x;
    int b = p / HW, hw = p % HW;
    const float* xc = xmid + (size_t)b * C * HW + hw;
    float xin[64];
#pragma unroll
    for (int c = 0; c < 64; c++) xin[c] = xc[c * HW];
#pragma unroll 1
    for (int co = 0; co < 64; co++) {
        float acc = bias[co];
        const float* wr = w + co * 64;
#pragma unroll
        for (int ci = 0; ci < 64; ci++) acc = fmaf(wr[ci], xin[ci], acc);
        float inv = inp[(size_t)(b * C + co) * HW + hw];
        y[(size_t)(b * C + co) * HW + hw] = inv + acc * beta[co];
    }
}

// K9: FFN: LN2 -> conv4 (128) -> gate -> conv5 (64) -> + y*gamma
__global__ void k9_ffn(const float* __restrict__ y, const float* __restrict__ lnw,
                       const float* __restrict__ lnb, const float* __restrict__ w4,
                       const float* __restrict__ b4, const float* __restrict__ w5,
                       const float* __restrict__ b5, const float* __restrict__ gamma,
                       float* __restrict__ out) {
    int p = blockIdx.x * 256 + threadIdx.x;
    int b = p / HW, hw = p % HW;
    const float* yc = y + (size_t)b * C * HW + hw;
    float v[64];
    float s = 0.f, s2 = 0.f;
#pragma unroll
    for (int c = 0; c < 64; c++) {
        float f = yc[c * HW];
        v[c] = f; s += f; s2 += f * f;
    }
    float mu  = s * (1.f / 64.f);
    float var = fmaxf(s2 * (1.f / 64.f) - mu * mu, 0.f);
    float r   = rsqrtf(var + 1e-6f);
#pragma unroll
    for (int c = 0; c < 64; c++)
        v[c] = (v[c] - mu) * r * lnw[c] + lnb[c];

    float acc[64];
#pragma unroll
    for (int co = 0; co < 64; co++) acc[co] = b5[co];

#pragma unroll 1
    for (int j = 0; j < 64; j++) {
        float t1 = b4[j];
        float t2 = b4[64 + j];
        const float* w1 = w4 + j * 64;
        const float* w2 = w1 + 64 * 64;
#pragma unroll
        for (int ci = 0; ci < 64; ci++) {
            t1 = fmaf(w1[ci], v[ci], t1);
            t2 = fmaf(w2[ci], v[ci], t2);
        }
        float gj = t1 * t2;
#pragma unroll
        for (int co = 0; co < 64; co++)
            acc[co] = fmaf(w5[co * 64 + j], gj, acc[co]);
    }
#pragma unroll
    for (int co = 0; co < 64; co++) {
        float o = yc[co * HW] + acc[co] * gamma[co];
        out[(size_t)(b * C + co) * HW + hw] = o;
    }
}

extern "C" void kernel_launch(void* const* d_in, const int* in_sizes, int n_in,
                              void* d_out, int out_size, void* d_ws, size_t ws_size,
                              hipStream_t stream) {
    (void)in_sizes; (void)n_in; (void)out_size; (void)ws_size;

    const float* inp     = (const float*)d_in[0];
    const float* ln1_w   = (const float*)d_in[1];
    const float* ln1_b   = (const float*)d_in[2];
    const float* ln2_w   = (const float*)d_in[3];
    const float* ln2_b   = (const float*)d_in[4];
    const float* sca_w   = (const float*)d_in[5];
    const float* sca_b   = (const float*)d_in[6];
    const float* c11a_w  = (const float*)d_in[7];
    const float* c11a_b  = (const float*)d_in[8];
    const float* c11b_w  = (const float*)d_in[9];
    const float* c11b_b  = (const float*)d_in[10];
    const float* c2a_w   = (const float*)d_in[11];
    const float* c2a_b   = (const float*)d_in[12];
    const float* c2b_w   = (const float*)d_in[13];
    const float* c2b_b   = (const float*)d_in[14];
    const float* conv3_w = (const float*)d_in[15];
    const float* conv3_b = (const float*)d_in[16];
    const float* conv4_w = (const float*)d_in[17];
    const float* conv4_b = (const float*)d_in[18];
    const float* conv5_w = (const float*)d_in[19];
    const float* conv5_b = (const float*)d_in[20];
    const float* kb_w    = (const float*)d_in[21];
    const float* kb_b    = (const float*)d_in[22];
    const float* ga1     = (const float*)d_in[23];
    const float* attg    = (const float*)d_in[24];
    const float* beta    = (const float*)d_in[25];
    const float* gamma   = (const float*)d_in[26];

    // ---- ws arena (~33 MB) ----
    char* ws = (char*)d_ws;
    size_t off = 0;
    auto alloc = [&](size_t bytes) {
        void* r = ws + off;
        off += (bytes + 255) & ~(size_t)255;
        return r;
    };
    float* meanb = (float*)alloc(128 * 4);
    float* scab  = (float*)alloc(128 * 4);
    float* x1    = (float*)alloc((size_t)P * 64 * 4);   // 13.1 MB
    float* attb  = (float*)alloc((size_t)P * 32 * 4);   // 6.55 MB
    float* u1    = (float*)alloc((size_t)P * 64 * 4);   // 13.1 MB
    float* ufb   = x1;   // x1 dead after K5
    float* xmid  = u1;   // u1 dead after K6
    float* yb    = x1;   // ufb dead after K7

    k1_ln1   <<<P / 256, 256, 0, stream>>>(inp, ln1_w, ln1_b, x1);
    k2_mean  <<<B * C, 256, 0, stream>>>(x1, meanb);
    k3_sca   <<<1, 128, 0, stream>>>(sca_w, sca_b, meanb, scab);
    k4_att   <<<P / 256, 256, 0, stream>>>(x1, c2a_w, c2a_b, c2b_w, c2b_b, attg, attb);
    k5_u1    <<<P / 256, 256, 0, stream>>>(x1, c11a_w, c11a_b, u1);
    k6_uf    <<<P / 64, 256, 0, stream>>>(u1, c11b_w, c11b_b, ufb);
    k7_kba   <<<2 * (P / 64), 256, 0, stream>>>(attb, ufb, kb_w, kb_b, ga1, scab, xmid);
    k8_conv3 <<<P / 256, 256, 0, stream>>>(xmid, inp, conv3_w, conv3_b, beta, yb);
    k9_ffn   <<<P / 256, 256, 0, stream>>>(yb, ln2_w, ln2_b, conv4_w, conv4_b,
                                           conv5_w, conv5_b, gamma, (float*)d_out);
}

// Round 4
// 1086.637 us; speedup vs baseline: 1.3628x; 1.3628x over previous
//
#include <hip/hip_runtime.h>

#define DEVFN __device__ __forceinline__

constexpr int C   = 64;
constexpr int Hh  = 160, Ww = 160, HW = Hh * Ww;   // 25600
constexpr int B   = 2;
constexpr int P   = B * HW;                        // 51200
constexpr int NSET = 32;

// K1: LayerNorm over channels per pixel
__global__ void k1_ln1(const float* __restrict__ inp, const float* __restrict__ lnw,
                       const float* __restrict__ lnb, float* __restrict__ x1) {
    int p = blockIdx.x * 256 + threadIdx.x;
    int b = p / HW, hw = p % HW;
    const float* src = inp + (size_t)b * C * HW + hw;
    float v[64];
    float s = 0.f, s2 = 0.f;
#pragma unroll
    for (int c = 0; c < 64; c++) {
        float f = src[c * HW];
        v[c] = f; s += f; s2 += f * f;
    }
    float mu  = s * (1.f / 64.f);
    float var = fmaxf(s2 * (1.f / 64.f) - mu * mu, 0.f);
    float r   = rsqrtf(var + 1e-6f);
    float* dst = x1 + (size_t)b * C * HW + hw;
#pragma unroll
    for (int c = 0; c < 64; c++)
        dst[c * HW] = (v[c] - mu) * r * lnw[c] + lnb[c];
}

// K2: spatial mean of x1 per (b,c)
__global__ void k2_mean(const float* __restrict__ x1, float* __restrict__ meanb) {
    int bc = blockIdx.x;                         // 0..127
    const float* src = x1 + (size_t)bc * HW;
    float s = 0.f;
    for (int i = threadIdx.x; i < HW; i += 256) s += src[i];
#pragma unroll
    for (int o = 32; o > 0; o >>= 1) s += __shfl_down(s, o);
    __shared__ float red[4];
    if ((threadIdx.x & 63) == 0) red[threadIdx.x >> 6] = s;
    __syncthreads();
    if (threadIdx.x == 0)
        meanb[bc] = (red[0] + red[1] + red[2] + red[3]) * (1.f / HW);
}

// K3: sca = sca_w @ mean + sca_b   [B,64]
__global__ void k3_sca(const float* __restrict__ scaw, const float* __restrict__ scab_,
                       const float* __restrict__ meanb, float* __restrict__ sca) {
    int t = threadIdx.x;
    if (t >= 128) return;
    int b = t >> 6, c = t & 63;
    float acc = scab_[c];
#pragma unroll
    for (int k = 0; k < 64; k++)
        acc = fmaf(scaw[c * 64 + k], meanb[b * 64 + k], acc);
    sca[t] = acc;
}

// helper for K4: 3x3 grouped conv taps (groups=32, 2 in-ch per out-ch)
template <bool INT_>
DEVFN void att_taps(const float* __restrict__ xb, int h, int w,
                    const float* __restrict__ c2aw, const float* __restrict__ c2ab,
                    float* t) {
#pragma unroll
    for (int o = 0; o < 32; o++) {
        float acc = c2ab[o];
#pragma unroll
        for (int k = 0; k < 2; k++) {
            const float* xc = xb + (size_t)(2 * o + k) * HW;
            const float* wr = c2aw + (o * 2 + k) * 9;
#pragma unroll
            for (int kh = 0; kh < 3; kh++) {
                int y = h + kh - 1;
#pragma unroll
                for (int kw = 0; kw < 3; kw++) {
                    int x = w + kw - 1;
                    if (INT_ || ((unsigned)y < (unsigned)Hh && (unsigned)x < (unsigned)Ww))
                        acc = fmaf(wr[kh * 3 + kw], xc[y * Ww + x], acc);
                }
            }
        }
        t[o] = acc;
    }
}

// K4: att = (1x1 conv(simple_gate(grouped 3x3 conv(x1)))) * attgamma
__global__ void k4_att(const float* __restrict__ x1, const float* __restrict__ c2aw,
                       const float* __restrict__ c2ab, const float* __restrict__ c2bw,
                       const float* __restrict__ c2bb, const float* __restrict__ attg,
                       float* __restrict__ att) {
    int p = blockIdx.x * 256 + threadIdx.x;
    int b = p / HW, hw = p % HW, h = hw / Ww, w = hw % Ww;
    const float* xb = x1 + (size_t)b * C * HW;
    float t[32];
    bool interior = (h >= 1 && h < Hh - 1 && w >= 1 && w < Ww - 1);
    if (interior) att_taps<true>(xb, h, w, c2aw, c2ab, t);
    else          att_taps<false>(xb, h, w, c2aw, c2ab, t);
    float g[16];
#pragma unroll
    for (int c = 0; c < 16; c++) g[c] = t[c] * t[c + 16];
#pragma unroll 1
    for (int s = 0; s < 32; s++) {
        float acc = c2bb[s];
#pragma unroll
        for (int c = 0; c < 16; c++)
            acc = fmaf(c2bw[s * 16 + c], g[c], acc);
        att[(size_t)(b * NSET + s) * HW + hw] = acc * attg[s];
    }
}

// K5: u1 = 1x1 conv (64x64) of x1
__global__ void k5_u1(const float* __restrict__ x1, const float* __restrict__ w,
                      const float* __restrict__ bias, float* __restrict__ u1) {
    int p = blockIdx.x * 256 + threadIdx.x;
    int b = p / HW, hw = p % HW;
    const float* xc = x1 + (size_t)b * C * HW + hw;
    float xin[64];
#pragma unroll
    for (int c = 0; c < 64; c++) xin[c] = xc[c * HW];
    float* dst = u1 + (size_t)b * C * HW + hw;
#pragma unroll 1
    for (int co = 0; co < 64; co++) {
        float acc = bias[co];
        const float* wr = w + co * 64;
#pragma unroll
        for (int ci = 0; ci < 64; ci++) acc = fmaf(wr[ci], xin[ci], acc);
        dst[co * HW] = acc;
    }
}

// K6: uf = 5x5 grouped conv (groups=16, 4in/4out) of u1, pad=2
__global__ void k6_uf(const float* __restrict__ u1, const float* __restrict__ w,
                      const float* __restrict__ bias, float* __restrict__ uf) {
    int lane = threadIdx.x & 63, wq = threadIdx.x >> 6;
    int p = blockIdx.x * 64 + lane;
    int b = p / HW, hw = p % HW, h = hw / Ww, w_ = hw % Ww;
    bool interior = (h >= 2 && h < Hh - 2 && w_ >= 2 && w_ < Ww - 2);
#pragma unroll 1
    for (int gi = 0; gi < 4; gi++) {
        int g = wq * 4 + gi;
        float acc[4];
#pragma unroll
        for (int o = 0; o < 4; o++) acc[o] = bias[g * 4 + o];
#pragma unroll 1
        for (int cl = 0; cl < 4; cl++) {
            int ci = g * 4 + cl;
            const float* src = u1 + (size_t)(b * C + ci) * HW;
            float tv[25];
            if (interior) {
#pragma unroll
                for (int kh = 0; kh < 5; kh++)
#pragma unroll
                    for (int kw = 0; kw < 5; kw++)
                        tv[kh * 5 + kw] = src[(h + kh - 2) * Ww + (w_ + kw - 2)];
            } else {
#pragma unroll
                for (int kh = 0; kh < 5; kh++) {
                    int y = h + kh - 2;
#pragma unroll
                    for (int kw = 0; kw < 5; kw++) {
                        int x = w_ + kw - 2;
                        tv[kh * 5 + kw] =
                            ((unsigned)y < (unsigned)Hh && (unsigned)x < (unsigned)Ww)
                                ? src[y * Ww + x] : 0.f;
                    }
                }
            }
#pragma unroll
            for (int o = 0; o < 4; o++) {
                const float* wr = w + ((g * 4 + o) * 4 + cl) * 25;
#pragma unroll
                for (int tp = 0; tp < 25; tp++) acc[o] = fmaf(wr[tp], tv[tp], acc[o]);
            }
        }
        float* dst = uf + (size_t)(b * C + g * 4) * HW + hw;
#pragma unroll
        for (int o = 0; o < 4; o++) dst[o * HW] = acc[o];
    }
}

// K7: KBA + ga1 + residual uf + sca scaling   -> xmid
// Grid: 200 pixel-blocks x 8 group-pairs. Group index derives from blockIdx
// ONLY -> weight addresses are wave-uniform -> compiler emits s_load + FMAs
// with SGPR weight operand (the round-3 version keyed g off threadIdx and
// compiled to per-lane vector loads of identical addresses: VALUBusy 16%).
__global__ void k7_kba(const float* __restrict__ att, const float* __restrict__ uf,
                       const float* __restrict__ kbw, const float* __restrict__ kbb,
                       const float* __restrict__ ga1, const float* __restrict__ sca,
                       float* __restrict__ xmid) {
    int blk  = blockIdx.x;                 // 0..1599
    int pblk = blk % 200;
    int gp   = blk / 200;                  // 0..7 -> groups 2*gp, 2*gp+1
    int p  = pblk * 256 + threadIdx.x;
    int b  = p / HW, hw = p % HW, h = hw / Ww, w = hw % Ww;

    float a[32];
    const float* asrc = att + (size_t)b * NSET * HW + hw;
#pragma unroll
    for (int s = 0; s < 32; s++) a[s] = asrc[s * HW];

    bool interior = (h >= 1 && h < Hh - 1 && w >= 1 && w < Ww - 1);

#pragma unroll 1
    for (int gi = 0; gi < 2; gi++) {
        int g = gp * 2 + gi;               // uniform
        float u[36];
#pragma unroll
        for (int cl = 0; cl < 4; cl++) {
            const float* src = uf + (size_t)(b * C + g * 4 + cl) * HW;
            if (interior) {
#pragma unroll
                for (int kh = 0; kh < 3; kh++)
#pragma unroll
                    for (int kw = 0; kw < 3; kw++)
                        u[cl * 9 + kh * 3 + kw] = src[(h + kh - 1) * Ww + (w + kw - 1)];
            } else {
#pragma unroll
                for (int kh = 0; kh < 3; kh++) {
                    int y = h + kh - 1;
#pragma unroll
                    for (int kw = 0; kw < 3; kw++) {
                        int x = w + kw - 1;
                        u[cl * 9 + kh * 3 + kw] =
                            ((unsigned)y < (unsigned)Hh && (unsigned)x < (unsigned)Ww)
                                ? src[y * Ww + x] : 0.f;
                    }
                }
            }
        }
#pragma unroll 1
        for (int o = 0; o < 4; o++) {
            int co = g * 4 + o;            // uniform
            const float* wr = kbw + g * 144 + o * 36;   // uniform base
            float acc = 0.f;
#pragma unroll 1
            for (int s = 0; s < 32; s++) {
                const float* ws_ = wr + s * 2304;       // uniform
                float dot = ws_[0] * u[0];
#pragma unroll
                for (int i = 1; i < 36; i++) dot = fmaf(ws_[i], u[i], dot);
                acc = fmaf(a[s], dot, acc);
            }
            float bsum = 0.f;
#pragma unroll
            for (int s = 0; s < 32; s++)
                bsum = fmaf(a[s], kbb[s * 64 + co], bsum);   // uniform weight
            float outv = (acc + bsum) * ga1[co] + u[o * 9 + 4];
            outv *= sca[b * 64 + co];
            xmid[(size_t)(b * C + co) * HW + hw] = outv;
        }
    }
}

// K8: conv3 (1x1 64x64) + residual:  y = inp + conv3(xmid)*beta
__global__ void k8_conv3(const float* __restrict__ xmid, const float* __restrict__ inp,
                         const float* __restrict__ w, const float* __restrict__ bias,
                         const float* __restrict__ beta, float* __restrict__ y) {
    int p = blockIdx.x * 256 + threadIdx.x;
    int b = p / HW, hw = p % HW;
    const float* xc = xmid + (size_t)b * C * HW + hw;
    float xin[64];
#pragma unroll
    for (int c = 0; c < 64; c++) xin[c] = xc[c * HW];
#pragma unroll 1
    for (int co = 0; co < 64; co++) {
        float acc = bias[co];
        const float* wr = w + co * 64;
#pragma unroll
        for (int ci = 0; ci < 64; ci++) acc = fmaf(wr[ci], xin[ci], acc);
        float inv = inp[(size_t)(b * C + co) * HW + hw];
        y[(size_t)(b * C + co) * HW + hw] = inv + acc * beta[co];
    }
}

// K9: FFN: LN2 -> conv4 (128) -> gate -> conv5 (64) -> + y*gamma
__global__ void k9_ffn(const float* __restrict__ y, const float* __restrict__ lnw,
                       const float* __restrict__ lnb, const float* __restrict__ w4,
                       const float* __restrict__ b4, const float* __restrict__ w5,
                       const float* __restrict__ b5, const float* __restrict__ gamma,
                       float* __restrict__ out) {
    int p = blockIdx.x * 256 + threadIdx.x;
    int b = p / HW, hw = p % HW;
    const float* yc = y + (size_t)b * C * HW + hw;
    float v[64];
    float s = 0.f, s2 = 0.f;
#pragma unroll
    for (int c = 0; c < 64; c++) {
        float f = yc[c * HW];
        v[c] = f; s += f; s2 += f * f;
    }
    float mu  = s * (1.f / 64.f);
    float var = fmaxf(s2 * (1.f / 64.f) - mu * mu, 0.f);
    float r   = rsqrtf(var + 1e-6f);
#pragma unroll
    for (int c = 0; c < 64; c++)
        v[c] = (v[c] - mu) * r * lnw[c] + lnb[c];

    float acc[64];
#pragma unroll
    for (int co = 0; co < 64; co++) acc[co] = b5[co];

#pragma unroll 1
    for (int j = 0; j < 64; j++) {
        float t1 = b4[j];
        float t2 = b4[64 + j];
        const float* w1 = w4 + j * 64;
        const float* w2 = w1 + 64 * 64;
#pragma unroll
        for (int ci = 0; ci < 64; ci++) {
            t1 = fmaf(w1[ci], v[ci], t1);
            t2 = fmaf(w2[ci], v[ci], t2);
        }
        float gj = t1 * t2;
#pragma unroll
        for (int co = 0; co < 64; co++)
            acc[co] = fmaf(w5[co * 64 + j], gj, acc[co]);
    }
#pragma unroll
    for (int co = 0; co < 64; co++) {
        float o = yc[co * HW] + acc[co] * gamma[co];
        out[(size_t)(b * C + co) * HW + hw] = o;
    }
}

extern "C" void kernel_launch(void* const* d_in, const int* in_sizes, int n_in,
                              void* d_out, int out_size, void* d_ws, size_t ws_size,
                              hipStream_t stream) {
    (void)in_sizes; (void)n_in; (void)out_size; (void)ws_size;

    const float* inp     = (const float*)d_in[0];
    const float* ln1_w   = (const float*)d_in[1];
    const float* ln1_b   = (const float*)d_in[2];
    const float* ln2_w   = (const float*)d_in[3];
    const float* ln2_b   = (const float*)d_in[4];
    const float* sca_w   = (const float*)d_in[5];
    const float* sca_b   = (const float*)d_in[6];
    const float* c11a_w  = (const float*)d_in[7];
    const float* c11a_b  = (const float*)d_in[8];
    const float* c11b_w  = (const float*)d_in[9];
    const float* c11b_b  = (const float*)d_in[10];
    const float* c2a_w   = (const float*)d_in[11];
    const float* c2a_b   = (const float*)d_in[12];
    const float* c2b_w   = (const float*)d_in[13];
    const float* c2b_b   = (const float*)d_in[14];
    const float* conv3_w = (const float*)d_in[15];
    const float* conv3_b = (const float*)d_in[16];
    const float* conv4_w = (const float*)d_in[17];
    const float* conv4_b = (const float*)d_in[18];
    const float* conv5_w = (const float*)d_in[19];
    const float* conv5_b = (const float*)d_in[20];
    const float* kb_w    = (const float*)d_in[21];
    const float* kb_b    = (const float*)d_in[22];
    const float* ga1     = (const float*)d_in[23];
    const float* attg    = (const float*)d_in[24];
    const float* beta    = (const float*)d_in[25];
    const float* gamma   = (const float*)d_in[26];

    // ---- ws arena (~33 MB) ----
    char* ws = (char*)d_ws;
    size_t off = 0;
    auto alloc = [&](size_t bytes) {
        void* r = ws + off;
        off += (bytes + 255) & ~(size_t)255;
        return r;
    };
    float* meanb = (float*)alloc(128 * 4);
    float* scab  = (float*)alloc(128 * 4);
    float* x1    = (float*)alloc((size_t)P * 64 * 4);   // 13.1 MB
    float* attb  = (float*)alloc((size_t)P * 32 * 4);   // 6.55 MB
    float* u1    = (float*)alloc((size_t)P * 64 * 4);   // 13.1 MB
    float* ufb   = x1;   // x1 dead after K5
    float* xmid  = u1;   // u1 dead after K6
    float* yb    = x1;   // ufb dead after K7

    k1_ln1   <<<P / 256, 256, 0, stream>>>(inp, ln1_w, ln1_b, x1);
    k2_mean  <<<B * C, 256, 0, stream>>>(x1, meanb);
    k3_sca   <<<1, 128, 0, stream>>>(sca_w, sca_b, meanb, scab);
    k4_att   <<<P / 256, 256, 0, stream>>>(x1, c2a_w, c2a_b, c2b_w, c2b_b, attg, attb);
    k5_u1    <<<P / 256, 256, 0, stream>>>(x1, c11a_w, c11a_b, u1);
    k6_uf    <<<P / 64, 256, 0, stream>>>(u1, c11b_w, c11b_b, ufb);
    k7_kba   <<<1600, 256, 0, stream>>>(attb, ufb, kb_w, kb_b, ga1, scab, xmid);
    k8_conv3 <<<P / 256, 256, 0, stream>>>(xmid, inp, conv3_w, conv3_b, beta, yb);
    k9_ffn   <<<P / 256, 256, 0, stream>>>(yb, ln2_w, ln2_b, conv4_w, conv4_b,
                                           conv5_w, conv5_b, gamma, (float*)d_out);
}

// Round 5
// 812.602 us; speedup vs baseline: 1.8224x; 1.3372x over previous
//
#include <hip/hip_runtime.h>

#define DEVFN __device__ __forceinline__

constexpr int C   = 64;
constexpr int Hh  = 160, Ww = 160, HW = Hh * Ww;   // 25600
constexpr int B   = 2;
constexpr int P   = B * HW;                        // 51200
constexpr int NSET = 32;

// NOTE: every kernel carries __launch_bounds__(256). Without it hipcc
// assumes 1024-thread workgroups and caps VGPRs at 64 -> v[64]/acc[64]
// arrays spill to scratch (round-4 profile: k9 VALUBusy 2.5%, 380us).

// K1: LayerNorm over channels per pixel
__global__ __launch_bounds__(256) void k1_ln1(
        const float* __restrict__ inp, const float* __restrict__ lnw,
        const float* __restrict__ lnb, float* __restrict__ x1) {
    int p = blockIdx.x * 256 + threadIdx.x;
    int b = p / HW, hw = p % HW;
    const float* src = inp + (size_t)b * C * HW + hw;
    float v[64];
    float s = 0.f, s2 = 0.f;
#pragma unroll
    for (int c = 0; c < 64; c++) {
        float f = src[c * HW];
        v[c] = f; s += f; s2 += f * f;
    }
    float mu  = s * (1.f / 64.f);
    float var = fmaxf(s2 * (1.f / 64.f) - mu * mu, 0.f);
    float r   = rsqrtf(var + 1e-6f);
    float* dst = x1 + (size_t)b * C * HW + hw;
#pragma unroll
    for (int c = 0; c < 64; c++)
        dst[c * HW] = (v[c] - mu) * r * lnw[c] + lnb[c];
}

// K2: spatial mean of x1 per (b,c)
__global__ __launch_bounds__(256) void k2_mean(
        const float* __restrict__ x1, float* __restrict__ meanb) {
    int bc = blockIdx.x;                         // 0..127
    const float* src = x1 + (size_t)bc * HW;
    float s = 0.f;
    for (int i = threadIdx.x; i < HW; i += 256) s += src[i];
#pragma unroll
    for (int o = 32; o > 0; o >>= 1) s += __shfl_down(s, o);
    __shared__ float red[4];
    if ((threadIdx.x & 63) == 0) red[threadIdx.x >> 6] = s;
    __syncthreads();
    if (threadIdx.x == 0)
        meanb[bc] = (red[0] + red[1] + red[2] + red[3]) * (1.f / HW);
}

// K3: sca = sca_w @ mean + sca_b   [B,64]
__global__ __launch_bounds__(256) void k3_sca(
        const float* __restrict__ scaw, const float* __restrict__ scab_,
        const float* __restrict__ meanb, float* __restrict__ sca) {
    int t = threadIdx.x;
    if (t >= 128) return;
    int b = t >> 6, c = t & 63;
    float acc = scab_[c];
#pragma unroll
    for (int k = 0; k < 64; k++)
        acc = fmaf(scaw[c * 64 + k], meanb[b * 64 + k], acc);
    sca[t] = acc;
}

// helper for K4: 3x3 grouped conv taps (groups=32, 2 in-ch per out-ch)
template <bool INT_>
DEVFN void att_taps(const float* __restrict__ xb, int h, int w,
                    const float* __restrict__ c2aw, const float* __restrict__ c2ab,
                    float* t) {
#pragma unroll
    for (int o = 0; o < 32; o++) {
        float acc = c2ab[o];
#pragma unroll
        for (int k = 0; k < 2; k++) {
            const float* xc = xb + (size_t)(2 * o + k) * HW;
            const float* wr = c2aw + (o * 2 + k) * 9;
#pragma unroll
            for (int kh = 0; kh < 3; kh++) {
                int y = h + kh - 1;
#pragma unroll
                for (int kw = 0; kw < 3; kw++) {
                    int x = w + kw - 1;
                    if (INT_ || ((unsigned)y < (unsigned)Hh && (unsigned)x < (unsigned)Ww))
                        acc = fmaf(wr[kh * 3 + kw], xc[y * Ww + x], acc);
                }
            }
        }
        t[o] = acc;
    }
}

// K4: att = (1x1 conv(simple_gate(grouped 3x3 conv(x1)))) * attgamma
__global__ __launch_bounds__(256) void k4_att(
        const float* __restrict__ x1, const float* __restrict__ c2aw,
        const float* __restrict__ c2ab, const float* __restrict__ c2bw,
        const float* __restrict__ c2bb, const float* __restrict__ attg,
        float* __restrict__ att) {
    int p = blockIdx.x * 256 + threadIdx.x;
    int b = p / HW, hw = p % HW, h = hw / Ww, w = hw % Ww;
    const float* xb = x1 + (size_t)b * C * HW;
    float t[32];
    bool interior = (h >= 1 && h < Hh - 1 && w >= 1 && w < Ww - 1);
    if (interior) att_taps<true>(xb, h, w, c2aw, c2ab, t);
    else          att_taps<false>(xb, h, w, c2aw, c2ab, t);
    float g[16];
#pragma unroll
    for (int c = 0; c < 16; c++) g[c] = t[c] * t[c + 16];
#pragma unroll 1
    for (int s = 0; s < 32; s++) {
        float acc = c2bb[s];
#pragma unroll
        for (int c = 0; c < 16; c++)
            acc = fmaf(c2bw[s * 16 + c], g[c], acc);
        att[(size_t)(b * NSET + s) * HW + hw] = acc * attg[s];
    }
}

// K5: u1 = 1x1 conv (64x64) of x1
__global__ __launch_bounds__(256) void k5_u1(
        const float* __restrict__ x1, const float* __restrict__ w,
        const float* __restrict__ bias, float* __restrict__ u1) {
    int p = blockIdx.x * 256 + threadIdx.x;
    int b = p / HW, hw = p % HW;
    const float* xc = x1 + (size_t)b * C * HW + hw;
    float xin[64];
#pragma unroll
    for (int c = 0; c < 64; c++) xin[c] = xc[c * HW];
    float* dst = u1 + (size_t)b * C * HW + hw;
#pragma unroll 1
    for (int co = 0; co < 64; co++) {
        float acc = bias[co];
        const float* wr = w + co * 64;
#pragma unroll
        for (int ci = 0; ci < 64; ci++) acc = fmaf(wr[ci], xin[ci], acc);
        dst[co * HW] = acc;
    }
}

// K6: uf = 5x5 grouped conv (groups=16, 4in/4out) of u1, pad=2
__global__ __launch_bounds__(256) void k6_uf(
        const float* __restrict__ u1, const float* __restrict__ w,
        const float* __restrict__ bias, float* __restrict__ uf) {
    int lane = threadIdx.x & 63, wq = threadIdx.x >> 6;
    int p = blockIdx.x * 64 + lane;
    int b = p / HW, hw = p % HW, h = hw / Ww, w_ = hw % Ww;
    bool interior = (h >= 2 && h < Hh - 2 && w_ >= 2 && w_ < Ww - 2);
#pragma unroll 1
    for (int gi = 0; gi < 4; gi++) {
        int g = wq * 4 + gi;
        float acc[4];
#pragma unroll
        for (int o = 0; o < 4; o++) acc[o] = bias[g * 4 + o];
#pragma unroll 1
        for (int cl = 0; cl < 4; cl++) {
            int ci = g * 4 + cl;
            const float* src = u1 + (size_t)(b * C + ci) * HW;
            float tv[25];
            if (interior) {
#pragma unroll
                for (int kh = 0; kh < 5; kh++)
#pragma unroll
                    for (int kw = 0; kw < 5; kw++)
                        tv[kh * 5 + kw] = src[(h + kh - 2) * Ww + (w_ + kw - 2)];
            } else {
#pragma unroll
                for (int kh = 0; kh < 5; kh++) {
                    int y = h + kh - 2;
#pragma unroll
                    for (int kw = 0; kw < 5; kw++) {
                        int x = w_ + kw - 2;
                        tv[kh * 5 + kw] =
                            ((unsigned)y < (unsigned)Hh && (unsigned)x < (unsigned)Ww)
                                ? src[y * Ww + x] : 0.f;
                    }
                }
            }
#pragma unroll
            for (int o = 0; o < 4; o++) {
                const float* wr = w + ((g * 4 + o) * 4 + cl) * 25;
#pragma unroll
                for (int tp = 0; tp < 25; tp++) acc[o] = fmaf(wr[tp], tv[tp], acc[o]);
            }
        }
        float* dst = uf + (size_t)(b * C + g * 4) * HW + hw;
#pragma unroll
        for (int o = 0; o < 4; o++) dst[o * HW] = acc[o];
    }
}

// K7: KBA + ga1 + residual uf + sca scaling   -> xmid
// Grid: 200 pixel-blocks x 8 group-pairs; group index from blockIdx ONLY so
// weight addresses are wave-uniform (s_load + SGPR-operand FMA).
__global__ __launch_bounds__(256) void k7_kba(
        const float* __restrict__ att, const float* __restrict__ uf,
        const float* __restrict__ kbw, const float* __restrict__ kbb,
        const float* __restrict__ ga1, const float* __restrict__ sca,
        float* __restrict__ xmid) {
    int blk  = blockIdx.x;                 // 0..1599
    int pblk = blk % 200;
    int gp   = blk / 200;                  // 0..7 -> groups 2*gp, 2*gp+1
    int p  = pblk * 256 + threadIdx.x;
    int b  = p / HW, hw = p % HW, h = hw / Ww, w = hw % Ww;

    float a[32];
    const float* asrc = att + (size_t)b * NSET * HW + hw;
#pragma unroll
    for (int s = 0; s < 32; s++) a[s] = asrc[s * HW];

    bool interior = (h >= 1 && h < Hh - 1 && w >= 1 && w < Ww - 1);

#pragma unroll 1
    for (int gi = 0; gi < 2; gi++) {
        int g = gp * 2 + gi;               // uniform
        float u[36];
#pragma unroll
        for (int cl = 0; cl < 4; cl++) {
            const float* src = uf + (size_t)(b * C + g * 4 + cl) * HW;
            if (interior) {
#pragma unroll
                for (int kh = 0; kh < 3; kh++)
#pragma unroll
                    for (int kw = 0; kw < 3; kw++)
                        u[cl * 9 + kh * 3 + kw] = src[(h + kh - 1) * Ww + (w + kw - 1)];
            } else {
#pragma unroll
                for (int kh = 0; kh < 3; kh++) {
                    int y = h + kh - 1;
#pragma unroll
                    for (int kw = 0; kw < 3; kw++) {
                        int x = w + kw - 1;
                        u[cl * 9 + kh * 3 + kw] =
                            ((unsigned)y < (unsigned)Hh && (unsigned)x < (unsigned)Ww)
                                ? src[y * Ww + x] : 0.f;
                    }
                }
            }
        }
#pragma unroll 1
        for (int o = 0; o < 4; o++) {
            int co = g * 4 + o;            // uniform
            const float* wr = kbw + g * 144 + o * 36;   // uniform base
            float acc = 0.f;
#pragma unroll 1
            for (int s = 0; s < 32; s++) {
                const float* ws_ = wr + s * 2304;       // uniform
                float dot = ws_[0] * u[0];
#pragma unroll
                for (int i = 1; i < 36; i++) dot = fmaf(ws_[i], u[i], dot);
                acc = fmaf(a[s], dot, acc);
            }
            float bsum = 0.f;
#pragma unroll
            for (int s = 0; s < 32; s++)
                bsum = fmaf(a[s], kbb[s * 64 + co], bsum);   // uniform weight
            float outv = (acc + bsum) * ga1[co] + u[o * 9 + 4];
            outv *= sca[b * 64 + co];
            xmid[(size_t)(b * C + co) * HW + hw] = outv;
        }
    }
}

// K8: conv3 (1x1 64x64) + residual:  y = inp + conv3(xmid)*beta
__global__ __launch_bounds__(256) void k8_conv3(
        const float* __restrict__ xmid, const float* __restrict__ inp,
        const float* __restrict__ w, const float* __restrict__ bias,
        const float* __restrict__ beta, float* __restrict__ y) {
    int p = blockIdx.x * 256 + threadIdx.x;
    int b = p / HW, hw = p % HW;
    const float* xc = xmid + (size_t)b * C * HW + hw;
    float xin[64];
#pragma unroll
    for (int c = 0; c < 64; c++) xin[c] = xc[c * HW];
#pragma unroll 1
    for (int co = 0; co < 64; co++) {
        float acc = bias[co];
        const float* wr = w + co * 64;
#pragma unroll
        for (int ci = 0; ci < 64; ci++) acc = fmaf(wr[ci], xin[ci], acc);
        float inv = inp[(size_t)(b * C + co) * HW + hw];
        y[(size_t)(b * C + co) * HW + hw] = inv + acc * beta[co];
    }
}

// K9: FFN: LN2 -> conv4 (128) -> gate -> conv5 (64) -> + y*gamma
__global__ __launch_bounds__(256) void k9_ffn(
        const float* __restrict__ y, const float* __restrict__ lnw,
        const float* __restrict__ lnb, const float* __restrict__ w4,
        const float* __restrict__ b4, const float* __restrict__ w5,
        const float* __restrict__ b5, const float* __restrict__ gamma,
        float* __restrict__ out) {
    int p = blockIdx.x * 256 + threadIdx.x;
    int b = p / HW, hw = p % HW;
    const float* yc = y + (size_t)b * C * HW + hw;
    float v[64];
    float s = 0.f, s2 = 0.f;
#pragma unroll
    for (int c = 0; c < 64; c++) {
        float f = yc[c * HW];
        v[c] = f; s += f; s2 += f * f;
    }
    float mu  = s * (1.f / 64.f);
    float var = fmaxf(s2 * (1.f / 64.f) - mu * mu, 0.f);
    float r   = rsqrtf(var + 1e-6f);
#pragma unroll
    for (int c = 0; c < 64; c++)
        v[c] = (v[c] - mu) * r * lnw[c] + lnb[c];

    float acc[64];
#pragma unroll
    for (int co = 0; co < 64; co++) acc[co] = b5[co];

#pragma unroll 1
    for (int j = 0; j < 64; j++) {
        float t1 = b4[j];
        float t2 = b4[64 + j];
        const float* w1 = w4 + j * 64;
        const float* w2 = w1 + 64 * 64;
#pragma unroll
        for (int ci = 0; ci < 64; ci++) {
            t1 = fmaf(w1[ci], v[ci], t1);
            t2 = fmaf(w2[ci], v[ci], t2);
        }
        float gj = t1 * t2;
#pragma unroll
        for (int co = 0; co < 64; co++)
            acc[co] = fmaf(w5[co * 64 + j], gj, acc[co]);
    }
#pragma unroll
    for (int co = 0; co < 64; co++) {
        float o = yc[co * HW] + acc[co] * gamma[co];
        out[(size_t)(b * C + co) * HW + hw] = o;
    }
}

extern "C" void kernel_launch(void* const* d_in, const int* in_sizes, int n_in,
                              void* d_out, int out_size, void* d_ws, size_t ws_size,
                              hipStream_t stream) {
    (void)in_sizes; (void)n_in; (void)out_size; (void)ws_size;

    const float* inp     = (const float*)d_in[0];
    const float* ln1_w   = (const float*)d_in[1];
    const float* ln1_b   = (const float*)d_in[2];
    const float* ln2_w   = (const float*)d_in[3];
    const float* ln2_b   = (const float*)d_in[4];
    const float* sca_w   = (const float*)d_in[5];
    const float* sca_b   = (const float*)d_in[6];
    const float* c11a_w  = (const float*)d_in[7];
    const float* c11a_b  = (const float*)d_in[8];
    const float* c11b_w  = (const float*)d_in[9];
    const float* c11b_b  = (const float*)d_in[10];
    const float* c2a_w   = (const float*)d_in[11];
    const float* c2a_b   = (const float*)d_in[12];
    const float* c2b_w   = (const float*)d_in[13];
    const float* c2b_b   = (const float*)d_in[14];
    const float* conv3_w = (const float*)d_in[15];
    const float* conv3_b = (const float*)d_in[16];
    const float* conv4_w = (const float*)d_in[17];
    const float* conv4_b = (const float*)d_in[18];
    const float* conv5_w = (const float*)d_in[19];
    const float* conv5_b = (const float*)d_in[20];
    const float* kb_w    = (const float*)d_in[21];
    const float* kb_b    = (const float*)d_in[22];
    const float* ga1     = (const float*)d_in[23];
    const float* attg    = (const float*)d_in[24];
    const float* beta    = (const float*)d_in[25];
    const float* gamma   = (const float*)d_in[26];

    // ---- ws arena (~33 MB) ----
    char* ws = (char*)d_ws;
    size_t off = 0;
    auto alloc = [&](size_t bytes) {
        void* r = ws + off;
        off += (bytes + 255) & ~(size_t)255;
        return r;
    };
    float* meanb = (float*)alloc(128 * 4);
    float* scab  = (float*)alloc(128 * 4);
    float* x1    = (float*)alloc((size_t)P * 64 * 4);   // 13.1 MB
    float* attb  = (float*)alloc((size_t)P * 32 * 4);   // 6.55 MB
    float* u1    = (float*)alloc((size_t)P * 64 * 4);   // 13.1 MB
    float* ufb   = x1;   // x1 dead after K5
    float* xmid  = u1;   // u1 dead after K6
    float* yb    = x1;   // ufb dead after K7

    k1_ln1   <<<P / 256, 256, 0, stream>>>(inp, ln1_w, ln1_b, x1);
    k2_mean  <<<B * C, 256, 0, stream>>>(x1, meanb);
    k3_sca   <<<1, 128, 0, stream>>>(sca_w, sca_b, meanb, scab);
    k4_att   <<<P / 256, 256, 0, stream>>>(x1, c2a_w, c2a_b, c2b_w, c2b_b, attg, attb);
    k5_u1    <<<P / 256, 256, 0, stream>>>(x1, c11a_w, c11a_b, u1);
    k6_uf    <<<P / 64, 256, 0, stream>>>(u1, c11b_w, c11b_b, ufb);
    k7_kba   <<<1600, 256, 0, stream>>>(attb, ufb, kb_w, kb_b, ga1, scab, xmid);
    k8_conv3 <<<P / 256, 256, 0, stream>>>(xmid, inp, conv3_w, conv3_b, beta, yb);
    k9_ffn   <<<P / 256, 256, 0, stream>>>(yb, ln2_w, ln2_b, conv4_w, conv4_b,
                                           conv5_w, conv5_b, gamma, (float*)d_out);
}